// Round 8
// baseline (153.372 us; speedup 1.0000x reference)
//
#include <hip/hip_runtime.h>
#include <stdint.h>

// Problem constants
#define CC    1024
#define EE    320
#define KN    640         // G*E
#define DD    256
#define MTOT  16384       // B*T
#define NBLK  640         // GEMM grid
#define OUT4  2097152     // output float4 count
#define MARGIN 12.0f      // candidate gate: ~7 sigma of fp8-e4m3 K=1024 dot error

typedef __attribute__((ext_vector_type(8))) short short8;
typedef __attribute__((ext_vector_type(4))) float f32x4;
typedef __attribute__((ext_vector_type(2))) long longx2;

__device__ __forceinline__ unsigned int f32_orderable(float x) {
    unsigned int b = __float_as_uint(x);
    return (b & 0x80000000u) ? ~b : (b | 0x80000000u);
}

__global__ void init_slots_kernel(unsigned long long* __restrict__ slots) {
    if (threadIdx.x < 17) slots[threadIdx.x] = 0ull;
}

// ------------------- fused convert (fp8 e4m3) + zero-fill + slot init -------------------
// Fragment-pair-major fp8 layout (A2F8 from X, B2F8 from W):
//   punit = rowTile*16 + kc2   (rowTile = row/16, kc2 = k/64)  -- 1KB per punit
//   buf[punit*1024 + lane*16 + h*8 + j] =
//       fp8 of M[rowTile*16 + (lane&15)][kc2*64 + h*32 + (lane>>4)*8 + j]   (h = k-half)
// -> one punit = one wave-linear 1KB block = ONE global_load_lds(16) in the GEMM.
__global__ __launch_bounds__(256)
void convert_kernel(const float* __restrict__ X, const float* __restrict__ W,
                    unsigned char* __restrict__ A2F8, unsigned char* __restrict__ B2F8,
                    unsigned long long* __restrict__ slots, float* __restrict__ out) {
    const int bid = blockIdx.x;
    const int tid = threadIdx.x;
    {   // zero-fill share of output (4256 blocks x 512 float4s >= 2,097,152)
        f32x4 z = {0.f, 0.f, 0.f, 0.f};
#pragma unroll
        for (int j = 0; j < 2; j++) {
            int zidx = bid * 512 + j * 256 + tid;
            if (zidx < OUT4) __builtin_nontemporal_store(z, (f32x4*)out + zidx);
        }
    }
    const int lane = tid & 63;
    const float* src;
    unsigned char* dst;
    int punit;
    if (bid < 4096) {                      // X: 16384 punits (1024 rowTiles x 16 kc2)
        punit = bid * 4 + (tid >> 6);
        src = X; dst = A2F8;
    } else {                               // W: 640 punits -> 160 blocks
        if (bid == 4096 && tid < 17) slots[tid] = 0ull;   // 16 slots + counter
        punit = (bid - 4096) * 4 + (tid >> 6);
        src = W; dst = B2F8;
    }
    int rt = punit >> 4, kc2 = punit & 15;
    int row = rt * 16 + (lane & 15);
    int col = kc2 * 64 + ((lane >> 4) << 3);
    const float* p = src + (size_t)row * CC + col;
    float4 v0 = *(const float4*)p;
    float4 v1 = *(const float4*)(p + 4);
    float4 v2 = *(const float4*)(p + 32);
    float4 v3 = *(const float4*)(p + 36);
    int d0 = __builtin_amdgcn_cvt_pk_fp8_f32(v0.x, v0.y, 0, false);
    d0     = __builtin_amdgcn_cvt_pk_fp8_f32(v0.z, v0.w, d0, true);
    int d1 = __builtin_amdgcn_cvt_pk_fp8_f32(v1.x, v1.y, 0, false);
    d1     = __builtin_amdgcn_cvt_pk_fp8_f32(v1.z, v1.w, d1, true);
    int d2 = __builtin_amdgcn_cvt_pk_fp8_f32(v2.x, v2.y, 0, false);
    d2     = __builtin_amdgcn_cvt_pk_fp8_f32(v2.z, v2.w, d2, true);
    int d3 = __builtin_amdgcn_cvt_pk_fp8_f32(v3.x, v3.y, 0, false);
    d3     = __builtin_amdgcn_cvt_pk_fp8_f32(v3.z, v3.w, d3, true);
    *(int4*)(dst + (size_t)punit * 1024 + lane * 16) = make_int4(d0, d1, d2, d3);
}

// ------------------- LDS 2-phase fp8 MFMA GEMM + margin argmax + refine + scatter -----------
// T3-minimum structure (guide 5.5): per K=64 step, stage the NEXT step's 16 punits
// (8 A + 8 B, 1KB each) into the alternate LDS buffer via global_load_lds width-16
// (4 instrs/wave, fire-and-forget), then 8 conflict-free ds_read_b128 fragment loads +
// 32 MFMA from the CURRENT buffer, then ONE __syncthreads (its vmcnt drain lands after a
// full MFMA phase of slack). 16 phases total. This removes the per-wave global-latency
// chain that pinned the no-LDS schedule at 51us regardless of bytes/waves/placement
// (R5/R6/R7 evidence). R1's failure modes are gone: no reg-staging, no ds_write bank
// conflicts, no in-loop converts, 16 phases not 64.
// Epilogue: block-max -> candidates within MARGIN -> cooperative EXACT fp32 dot from
// X,W -> packed atomicMax. Last block (device counter) scatters the 16 codebook rows.
__global__ __launch_bounds__(256, 3)
void gemm_argmax_mfma(const unsigned char* __restrict__ A2F8,
                      const unsigned char* __restrict__ B2F8,
                      const float* __restrict__ X,
                      const float* __restrict__ W,
                      const float* __restrict__ bias,
                      const float* __restrict__ codebook,
                      float* __restrict__ out,
                      unsigned long long* __restrict__ slots,
                      unsigned int* __restrict__ counter) {
    __shared__ __align__(16) unsigned char lds[32768];   // 2 bufs x (8KB A + 8KB B)
    __shared__ float redf[4];
    __shared__ int cnt_s;
    __shared__ int cand_s[128];
    __shared__ unsigned int done_s;
    __shared__ unsigned long long s16[16];

    const int tid  = threadIdx.x;
    const int lane = tid & 63;
    const int wave = tid >> 6;

    // XCD swizzle: one XCD covers 16 m-tiles x all 5 n-tiles (n fastest) -> A2F8 L2 reuse.
    const int l   = blockIdx.x;        // 0..639
    const int xcd = l & 7;
    const int w   = l >> 3;
    const int mt  = xcd * 16 + w / 5;
    const int nt  = w % 5;
    const int m0 = mt * 128;
    const int n0 = nt * 128;

    const int wm = (wave >> 1) * 64;
    const int wn = (wave & 1) * 64;

    // staging sources for this wave: A row-tiles {wave, wave+4}, B row-tiles {wave, wave+4}
    // punit(rt, t) lives at rt*16384 + t*1024; per-lane source offset lane*16.
    const unsigned char* sA0 = A2F8 + (size_t)(((m0 >> 4) + wave)     ) * 16384 + lane * 16;
    const unsigned char* sA1 = A2F8 + (size_t)(((m0 >> 4) + wave + 4) ) * 16384 + lane * 16;
    const unsigned char* sB0 = B2F8 + (size_t)(((n0 >> 4) + wave)     ) * 16384 + lane * 16;
    const unsigned char* sB1 = B2F8 + (size_t)(((n0 >> 4) + wave + 4) ) * 16384 + lane * 16;
    // wave-uniform LDS destinations (HW adds lane*16)
    const int dA0 = wave * 1024;
    const int dA1 = (wave + 4) * 1024;
    const int dB0 = 8192 + wave * 1024;
    const int dB1 = 8192 + (wave + 4) * 1024;

    f32x4 acc[4][4] = {};

#define STAGE(BUF, T)                                                                     \
    {                                                                                     \
        __builtin_amdgcn_global_load_lds(                                                 \
            (const __attribute__((address_space(1))) void*)(sA0 + (size_t)(T) * 1024),    \
            (__attribute__((address_space(3))) void*)(lds + (BUF) + dA0), 16, 0, 0);      \
        __builtin_amdgcn_global_load_lds(                                                 \
            (const __attribute__((address_space(1))) void*)(sA1 + (size_t)(T) * 1024),    \
            (__attribute__((address_space(3))) void*)(lds + (BUF) + dA1), 16, 0, 0);      \
        __builtin_amdgcn_global_load_lds(                                                 \
            (const __attribute__((address_space(1))) void*)(sB0 + (size_t)(T) * 1024),    \
            (__attribute__((address_space(3))) void*)(lds + (BUF) + dB0), 16, 0, 0);      \
        __builtin_amdgcn_global_load_lds(                                                 \
            (const __attribute__((address_space(1))) void*)(sB1 + (size_t)(T) * 1024),    \
            (__attribute__((address_space(3))) void*)(lds + (BUF) + dB1), 16, 0, 0);      \
    }

#define COMPUTE(BUF)                                                                      \
    {                                                                                     \
        longx2 af[4], bfr[4];                                                             \
        _Pragma("unroll")                                                                 \
        for (int t = 0; t < 4; t++) {                                                     \
            af[t]  = *(const longx2*)(lds + (BUF) + (((wm >> 4) + t) << 10) + lane * 16); \
            bfr[t] = *(const longx2*)(lds + (BUF) + 8192 + (((wn >> 4) + t) << 10) + lane * 16); \
        }                                                                                 \
        _Pragma("unroll")                                                                 \
        for (int h = 0; h < 2; h++)                                                       \
            _Pragma("unroll")                                                             \
            for (int ti = 0; ti < 4; ti++)                                                \
                _Pragma("unroll")                                                         \
                for (int tj = 0; tj < 4; tj++)                                            \
                    acc[ti][tj] = __builtin_amdgcn_mfma_f32_16x16x32_fp8_fp8(             \
                        af[ti][h], bfr[tj][h], acc[ti][tj], 0, 0, 0);                     \
    }

    // prologue: stage step 0 into buf0
    STAGE(0, 0)
    __syncthreads();

    // 16 phases of K=64 (K=1024 total), ping-pong buffers, 1 barrier/phase
    for (int it2 = 0; it2 < 7; it2++) {
        STAGE(16384, 2 * it2 + 1) COMPUTE(0)     __syncthreads();
        STAGE(0,     2 * it2 + 2) COMPUTE(16384) __syncthreads();
    }
    STAGE(16384, 15) COMPUTE(0) __syncthreads();   // t = 14
    COMPUTE(16384)                                 // t = 15 (no stage)

#undef STAGE
#undef COMPUTE

    // ---- epilogue: block max of approx logits ----
    // C/D layout (16x16x32, dtype-independent): col = lane&15, row = (lane>>4)*4 + reg
    float bias4[4];
#pragma unroll
    for (int tj = 0; tj < 4; tj++) bias4[tj] = bias[n0 + wn + tj * 16 + (lane & 15)];

    float vmax = -3.0e38f;
#pragma unroll
    for (int ti = 0; ti < 4; ti++)
#pragma unroll
        for (int tj = 0; tj < 4; tj++)
#pragma unroll
            for (int r = 0; r < 4; r++)
                vmax = fmaxf(vmax, acc[ti][tj][r] + bias4[tj]);
#pragma unroll
    for (int off = 32; off > 0; off >>= 1)
        vmax = fmaxf(vmax, __shfl_down(vmax, off, 64));
    if (lane == 0) redf[wave] = vmax;
    if (tid == 0) cnt_s = 0;
    __syncthreads();
    float bm = fmaxf(fmaxf(redf[0], redf[1]), fmaxf(redf[2], redf[3]));
    float thresh = bm - MARGIN;

    // ---- collect candidates within MARGIN of block max ----
#pragma unroll
    for (int ti = 0; ti < 4; ti++) {
#pragma unroll
        for (int r = 0; r < 4; r++) {
            int m = m0 + wm + ti * 16 + (lane >> 4) * 4 + r;
#pragma unroll
            for (int tj = 0; tj < 4; tj++) {
                float v = acc[ti][tj][r] + bias4[tj];
                if (v >= thresh) {
                    int n = n0 + wn + tj * 16 + (lane & 15);
                    int idx = atomicAdd(&cnt_s, 1);
                    if (idx < 128) cand_s[idx] = (m << 10) | n;
                }
            }
        }
    }
    __syncthreads();
    int cnt = cnt_s < 128 ? cnt_s : 128;

    // ---- exact fp32 refine of each candidate (cooperative 1024-dot) ----
    for (int i = 0; i < cnt; i++) {
        int mc = cand_s[i] >> 10;
        int nc = cand_s[i] & 1023;
        float4 xv = *(const float4*)(X + (size_t)mc * CC + tid * 4);
        float4 wv = *(const float4*)(W + (size_t)nc * CC + tid * 4);
        float p = xv.x * wv.x + xv.y * wv.y + xv.z * wv.z + xv.w * wv.w;
#pragma unroll
        for (int off = 32; off > 0; off >>= 1) p += __shfl_down(p, off, 64);
        if (lane == 0) redf[wave] = p;
        __syncthreads();
        if (tid == 0) {
            float tot = redf[0] + redf[1] + redf[2] + redf[3] + bias[nc];
            unsigned int c = (unsigned int)((mc & 1023) * KN + nc);
            unsigned long long pk =
                ((unsigned long long)f32_orderable(tot) << 32) |
                (unsigned long long)(~c);
            atomicMax(slots + (mc >> 10), pk);
        }
        __syncthreads();
    }

    if (tid == 0) {
        __threadfence();
        done_s = atomicAdd(counter, 1u);
    }
    __syncthreads();

    // ---- last block scatters the 16 codebook rows ----
    if (done_s == NBLK - 1) {
        if (tid < 16) s16[tid] = atomicAdd(slots + tid, 0ull);   // coherent cross-XCD read
        __syncthreads();
        int rr  = tid >> 4;
        int seg = tid & 15;
        unsigned long long p = s16[rr];
        unsigned int c = ~(unsigned int)(p & 0xFFFFFFFFull);
        int tl = (int)(c / KN);
        int kg = (int)(c % KN);
        int b  = rr >> 1, h = rr & 1;
        int nstar = b * 2048 + h * 1024 + tl;
        int g = kg / EE;
        const float4* src = (const float4*)(codebook + (size_t)kg * DD) + seg * 4;
        float4* dst = (float4*)(out + (size_t)nstar * 512 + (size_t)g * DD) + seg * 4;
#pragma unroll
        for (int j = 0; j < 4; j++) dst[j] = src[j];
    }
}

// ------------------- fallback-only kernels (ws too small; not used in practice) ------------
__global__ __launch_bounds__(256)
void zs_kernel(const unsigned long long* __restrict__ slots,
               const float* __restrict__ codebook,
               float4* __restrict__ out4) {
    int i4 = blockIdx.x * 256 + threadIdx.x;
    int n  = i4 >> 7;
    int c4 = i4 & 127;
    int b  = n >> 11;
    int h  = (n >> 10) & 1;
    unsigned long long p = slots[b * 2 + h];
    unsigned int c = ~(unsigned int)(p & 0xFFFFFFFFull);
    int tl = (int)(c / KN);
    int kg = (int)(c % KN);
    int nstar = b * 2048 + h * 1024 + tl;
    int g = kg / EE;
    float4 v = make_float4(0.f, 0.f, 0.f, 0.f);
    if (n == nstar && (c4 >> 6) == g)
        v = ((const float4*)codebook)[kg * 64 + (c4 & 63)];
    out4[i4] = v;
}

#define BM 128
#define BN 64
#define BK 32
#define LDA (BM + 4)
#define LDB (BN + 4)

__global__ __launch_bounds__(128)
void gemm_argmax_f32(const float* __restrict__ X, const float* __restrict__ W,
                     const float* __restrict__ bias,
                     unsigned long long* __restrict__ slots) {
    __shared__ float Asf[BK][LDA];
    __shared__ float Bsf[BK][LDB];
    const int tid = threadIdx.x;
    const int m0 = blockIdx.y * BM;
    const int n0 = blockIdx.x * BN;
    const int tx = tid & 7, ty = tid >> 3;
    float acc[8][8];
#pragma unroll
    for (int i = 0; i < 8; i++)
#pragma unroll
        for (int j = 0; j < 8; j++) acc[i][j] = 0.0f;
    const int lm = tid >> 3, lk = (tid & 7) * 4;
    const float* Xb = X + (size_t)m0 * CC;
    const float* Wb = W + (size_t)n0 * CC;
    for (int k0 = 0; k0 < CC; k0 += BK) {
#pragma unroll
        for (int r = 0; r < 8; r++) {
            int m = r * 16 + lm;
            float4 v = *(const float4*)(Xb + (size_t)m * CC + k0 + lk);
            Asf[lk + 0][m] = v.x; Asf[lk + 1][m] = v.y; Asf[lk + 2][m] = v.z; Asf[lk + 3][m] = v.w;
        }
#pragma unroll
        for (int r = 0; r < 4; r++) {
            int m = r * 16 + lm;
            float4 v = *(const float4*)(Wb + (size_t)m * CC + k0 + lk);
            Bsf[lk + 0][m] = v.x; Bsf[lk + 1][m] = v.y; Bsf[lk + 2][m] = v.z; Bsf[lk + 3][m] = v.w;
        }
        __syncthreads();
#pragma unroll
        for (int kk = 0; kk < BK; kk++) {
            float4 A0 = *(const float4*)&Asf[kk][ty * 8];
            float4 A1 = *(const float4*)&Asf[kk][ty * 8 + 4];
            float4 B0 = *(const float4*)&Bsf[kk][tx * 8];
            float4 B1 = *(const float4*)&Bsf[kk][tx * 8 + 4];
            float a[8] = {A0.x, A0.y, A0.z, A0.w, A1.x, A1.y, A1.z, A1.w};
            float b[8] = {B0.x, B0.y, B0.z, B0.w, B1.x, B1.y, B1.z, B1.w};
#pragma unroll
            for (int i = 0; i < 8; i++)
#pragma unroll
                for (int j = 0; j < 8; j++) acc[i][j] = fmaf(a[i], b[j], acc[i][j]);
        }
        __syncthreads();
    }
    unsigned long long best = 0ull;
#pragma unroll
    for (int i = 0; i < 8; i++) {
        int mg = m0 + ty * 8 + i;
        int tl = mg & 1023;
#pragma unroll
        for (int j = 0; j < 8; j++) {
            int kg = n0 + tx * 8 + j;
            float v = acc[i][j] + bias[kg];
            unsigned int c = (unsigned int)(tl * KN + kg);
            unsigned long long p = ((unsigned long long)f32_orderable(v) << 32) |
                                   (unsigned long long)(~c);
            if (p > best) best = p;
        }
    }
#pragma unroll
    for (int off = 32; off > 0; off >>= 1) {
        unsigned long long o = __shfl_down(best, off, 64);
        if (o > best) best = o;
    }
    __shared__ unsigned long long red2[2];
    if ((tid & 63) == 0) red2[tid >> 6] = best;
    __syncthreads();
    if (tid == 0) {
        unsigned long long b0 = red2[0], b1 = red2[1];
        atomicMax(slots + (m0 >> 10), b0 > b1 ? b0 : b1);
    }
}

extern "C" void kernel_launch(void* const* d_in, const int* in_sizes, int n_in,
                              void* d_out, int out_size, void* d_ws, size_t ws_size,
                              hipStream_t stream) {
    const float* X        = (const float*)d_in[0];  // (8,2048,1024)
    const float* W        = (const float*)d_in[1];  // (640,1024)
    const float* bias     = (const float*)d_in[2];  // (640,)
    const float* codebook = (const float*)d_in[3];  // (640,256)
    float* out = (float*)d_out;                     // (8,2048,512) fp32

    unsigned long long* slots = (unsigned long long*)d_ws;   // [0..15] slots, [16] counter
    unsigned int* counter = (unsigned int*)(slots + 16);
    const size_t A_off   = 256;
    const size_t A_bytes = (size_t)MTOT * CC;           // 16,777,216 (fp8 frag-pair-major)
    const size_t B_off   = A_off + A_bytes;
    const size_t B_bytes = (size_t)KN * CC;             // 655,360
    const size_t need = B_off + B_bytes;

    if (ws_size >= need) {
        unsigned char* A2F8 = (unsigned char*)d_ws + A_off;
        unsigned char* B2F8 = (unsigned char*)d_ws + B_off;
        hipLaunchKernelGGL(convert_kernel, dim3(4096 + 160), dim3(256), 0, stream,
                           X, W, A2F8, B2F8, slots, out);
        hipLaunchKernelGGL(gemm_argmax_mfma, dim3(NBLK), dim3(256), 0, stream,
                           A2F8, B2F8, X, W, bias, codebook, out, slots, counter);
    } else {
        hipLaunchKernelGGL(init_slots_kernel, dim3(1), dim3(64), 0, stream, slots);
        hipLaunchKernelGGL(gemm_argmax_f32, dim3(KN / BN, MTOT / BM), dim3(128), 0, stream,
                           X, W, bias, slots);
        hipLaunchKernelGGL(zs_kernel, dim3(OUT4 / 256), dim3(256), 0, stream,
                           slots, codebook, (float4*)out);
    }
}